// Round 12
// baseline (415.059 us; speedup 1.0000x reference)
//
#include <hip/hip_runtime.h>
#include <math.h>

// ---------------------------------------------------------------------------
// B=16, NP1=65, BT=1040, Mg=256, D=512, H=8, DH=64, L=3, DFF=2048
// R20: dispatches 13 -> 10. fused_ffx (65 blk x 16 waves): ff1+GELU+ff2+
// residual+LN2 in one kernel, H in LDS in two 1024-col chunks (32KB; LDS
// total 50KB). Fixes R17's killers: 2-deep prefetch on ALL streams, 65
// blocks (260MB/layer weight re-stream, +4us vs split), chunked H. ff2
// accumulates K-ascending across chunks -> bit-identical to split path.
// Layer 2 keeps R19's in-kernel u/h head + closed-form projection.
// Evidence: only dispatch-removal ever won big (R13->R15: -3 disp = -41us,
// ~14us/boundary); prefetch depth/blocks/waves all ~null.
// ---------------------------------------------------------------------------

#define BT   1040
#define NP1  65
#define Dm   512
#define MG   256

typedef short short8 __attribute__((ext_vector_type(8)));
typedef float f32x4  __attribute__((ext_vector_type(4)));
typedef unsigned short u16;

// packed u16 index of element (r, c) in a [R][C] bf16 matrix, KB = C/64
__device__ __forceinline__ size_t pidx(int r, int c, int KB) {
  return ((size_t)((r >> 6) * KB + (c >> 6)) * 8 + ((c & 63) >> 3)) * 512
       + (size_t)((r & 63) * 8 + (c & 7));
}

__device__ __forceinline__ u16 f2bf(float f) {
  unsigned int u = __float_as_uint(f);
  u += 0x7FFF + ((u >> 16) & 1);          // RNE
  return (u16)(u >> 16);
}

__device__ __forceinline__ float bf2f(u16 v) {
  return __uint_as_float((unsigned int)v << 16);
}

__device__ __forceinline__ float gelu_exact(float x) {
  return 0.5f * x * (1.0f + erff(x * 0.70710678118654752f));
}

__device__ __forceinline__ void async16(const u16* g, u16* l) {
  __builtin_amdgcn_global_load_lds(
      (const __attribute__((address_space(1))) unsigned int*)g,
      (__attribute__((address_space(3))) unsigned int*)l, 16, 0, 0);
}

__device__ __forceinline__ float wred(float v) {
#pragma unroll
  for (int o = 32; o; o >>= 1) v += __shfl_xor(v, o, 64);
  return v;
}

__device__ __forceinline__ float block_reduce_sum(float v, float* s) {
#pragma unroll
  for (int off = 32; off; off >>= 1) v += __shfl_down(v, off, 64);
  int lane = threadIdx.x & 63, wid = threadIdx.x >> 6;
  __syncthreads();
  if (lane == 0) s[wid] = v;
  __syncthreads();
  return s[0] + s[1] + s[2] + s[3];
}

// closed-form expected grid value under weights exp(-a*x_j/eps), x_j uniform:
__device__ __forceinline__ float f_closed(float a) {
  const float tf = 2.3529411765f;     // (6/255)*100
  float t = a * tf;
  float s = fabsf(t);
  float E;
  if (s < 1e-4f) {
    E = 127.5f - 5461.25f * t;        // series; kappa2=(256^2-1)/12
  } else {
    float u = s * 256.0f;
    float term2 = (u < 80.0f) ? 256.0f / expm1f(u) : 0.0f;
    float Epos = 1.0f / expm1f(s) - term2;
    E = (t > 0.0f) ? Epos : 255.0f - Epos;
  }
  return -3.0f + 0.0235294118f * E;   // delta = 6/255
}

// ---------------------------------------------------------------------------
// prep: blocks [0,512) convert+PACK weights fp32->bf16; [512,772) embed
// ---------------------------------------------------------------------------
__global__ __launch_bounds__(256) void prep_kernel(
    const float* __restrict__ qkv_w, const float* __restrict__ out_w,
    const float* __restrict__ ff1_w, const float* __restrict__ ff2_w,
    const float* __restrict__ u_w,   const float* __restrict__ h_w,
    u16* __restrict__ wdst,
    const float* __restrict__ marg, const float* __restrict__ conv_w,
    const float* __restrict__ conv_b, const float* __restrict__ fc_w,
    const float* __restrict__ fc_b, const float* __restrict__ g,
    const float* __restrict__ bb, const float* __restrict__ pos,
    float* __restrict__ xs, u16* __restrict__ xsb)
{
  const int tid = threadIdx.x;
  if (blockIdx.x < 512) {
    const size_t O1 = 2359296, O2 = 3145728, O3 = 6291456;
    const size_t O4 = 9437184, O5 = 9568256, TOT4 = 9699328 / 4;
    for (size_t e4 = (size_t)blockIdx.x * 256 + tid; e4 < TOT4;
         e4 += (size_t)512 * 256) {
      size_t e = e4 * 4;
      const float* src; size_t base; int n, k, KB;
      if (e < O1)      { size_t r = e;      src = qkv_w + r; base = 0;
                         n = (int)(r >> 9);  k = (int)(r & 511);  KB = 8; }
      else if (e < O2) { size_t r = e - O1; src = out_w + r; base = O1;
                         n = (int)(r >> 9);  k = (int)(r & 511);  KB = 8; }
      else if (e < O3) { size_t r = e - O2; src = ff1_w + r; base = O2;
                         n = (int)(r >> 9);  k = (int)(r & 511);  KB = 8; }
      else if (e < O4) { size_t r = e - O3; src = ff2_w + r; base = O3;
                         n = (int)(r >> 11); k = (int)(r & 2047); KB = 32; }
      else if (e < O5) { size_t r = e - O4; src = u_w + r;   base = O4;
                         n = (int)(r >> 9);  k = (int)(r & 511);  KB = 8; }
      else             { size_t r = e - O5; src = h_w + r;   base = O4;
                         n = 256 + (int)(r >> 9); k = (int)(r & 511); KB = 8; }
      float4 v = *(const float4*)src;
      unsigned int lo = (unsigned int)f2bf(v.x) | ((unsigned int)f2bf(v.y) << 16);
      unsigned int hi = (unsigned int)f2bf(v.z) | ((unsigned int)f2bf(v.w) << 16);
      *(uint2*)(wdst + base + pidx(n, k, KB)) = make_uint2(lo, hi);
    }
    return;
  }
  // ---- embed: 4 tokens per block ----
  __shared__ float es[4][128];
  __shared__ float sS[4];
  __shared__ float edge[4][4];
  __shared__ float red[4];
  const int t0 = (blockIdx.x - 512) * 4;
  const int lane = tid & 63, wave = tid >> 6;
  {
    float4 mv = *(const float4*)(marg + (size_t)(t0 + wave) * MG + lane * 4);
    float S = wred(mv.x + mv.y + mv.z + mv.w);
    if (lane == 0) sS[wave] = S;
  }
  if (tid < 16) {
    int k = tid >> 2, e = tid & 3;
    int idx = (e < 2) ? e : (e + 252);       // 0,1,254,255
    edge[k][e] = marg[(size_t)(t0 + k) * MG + idx];
  }
  __syncthreads();
  if (tid < 128) {
    int o = tid;
    float w0 = conv_w[o*5+0], w1 = conv_w[o*5+1], w2 = conv_w[o*5+2];
    float w3 = conv_w[o*5+3], w4 = conv_w[o*5+4], cb = conv_b[o];
#pragma unroll
    for (int k = 0; k < 4; ++k) {
      float S = sS[k];
      float x0 = edge[k][0], x1 = edge[k][1], x254 = edge[k][2], x255 = edge[k][3];
      es[k][o] = (w0*(S - x254 - x255) + w1*(S - x255) + w2*S
                + w3*(S - x0) + w4*(S - x0 - x1)) * (1.0f/256.0f) + cb;
    }
  }
  __syncthreads();
  float b0 = fc_b[tid], b1 = fc_b[tid + 256];
  float z[4][2];
#pragma unroll
  for (int k = 0; k < 4; ++k) { z[k][0] = b0; z[k][1] = b1; }
#pragma unroll 4
  for (int o = 0; o < 128; ++o) {
    float f0 = fc_w[(size_t)o*Dm + tid];
    float f1 = fc_w[(size_t)o*Dm + tid + 256];
#pragma unroll
    for (int k = 0; k < 4; ++k) {
      float e = es[k][o];
      z[k][0] += e * f0; z[k][1] += e * f1;
    }
  }
  float g0 = g[tid], g1 = g[tid+256], e0 = bb[tid], e1 = bb[tid+256];
#pragma unroll
  for (int k = 0; k < 4; ++k) {
    float mu = block_reduce_sum(z[k][0] + z[k][1], red) * (1.0f/512.0f);
    float d0 = z[k][0] - mu, d1 = z[k][1] - mu;
    float var = block_reduce_sum(d0*d0 + d1*d1, red) * (1.0f/512.0f);
    float inv = rsqrtf(var + 1e-5f);
    int t = t0 + k, p = t % NP1;
    float y0 = gelu_exact(d0*inv*g0 + e0) + pos[(size_t)p*Dm + tid];
    float y1 = gelu_exact(d1*inv*g1 + e1) + pos[(size_t)p*Dm + tid + 256];
    xs[(size_t)t*Dm + tid]        = y0;
    xs[(size_t)t*Dm + tid + 256]  = y1;
    xsb[pidx(t, tid, 8)]          = f2bf(y0);
    xsb[pidx(t, tid + 256, 8)]    = f2bf(y1);
  }
}

// ---------------------------------------------------------------------------
// fused_qkv_attn: one block per (b,h). MFMA computes Q,K,V (65x192, K=512)
// from packed xsb / qkv_w. Q,K fp32 LDS; V bf16 LDS; scores alias the A-stage
// buffer (flat u16 buf + casts). obufb packed.
// ---------------------------------------------------------------------------
__global__ __launch_bounds__(256) void fused_qkv_attn(
    const u16* __restrict__ xsb, const u16* __restrict__ qkvw,
    const float* __restrict__ qkvb, u16* __restrict__ obufb)
{
  __shared__ alignas(16) u16 stbuf[10240];       // 20480 B: A-stage | scores
  __shared__ alignas(16) float qf[65][67];
  __shared__ alignas(16) float kf[65][67];
  __shared__ alignas(16) u16   vb[65][68];
  u16* sta = stbuf;                              // [kg 16][row 80][8]
  float (*ss)[67] = (float (*)[67])stbuf;        // [65][67] = 17420 B, fits

  const int b = blockIdx.x >> 3, h = blockIdx.x & 7;
  const int tid = threadIdx.x, lane = tid & 63, wave = tid >> 6;
  const int l15 = lane & 15, q = lane >> 4;
  const int rowg0 = b * NP1;

  f32x4 acc[5][3];
#pragma unroll
  for (int rt = 0; rt < 5; ++rt)
#pragma unroll
    for (int j = 0; j < 3; ++j) acc[rt][j] = (f32x4){0,0,0,0};

  // ---- GEMM: K=512 in 4 chunks of 128 ----
  for (int ch = 0; ch < 4; ++ch) {
    __syncthreads();
    for (int idx = tid; idx < 16 * 80; idx += 256) {
      int kg = idx / 80, rl = idx - kg * 80;
      int r = rowg0 + min(rl, 64);
      async16(xsb + pidx(r, ch * 128 + kg * 8, 8), &sta[(size_t)idx * 8]);
    }
    asm volatile("s_waitcnt vmcnt(0)" ::: "memory");
    __syncthreads();

    short8 bcur[3], bnxt[3];
#pragma unroll
    for (int j = 0; j < 3; ++j) {
      int f = wave * 3 + j, region = f >> 2, sub = f & 3;
      int nb = region * 8 + h, nn = sub * 16 + l15;
      int kk = ch * 128 + q * 8;
      int kbg = kk >> 6, cc = (kk & 63) >> 3;
      bcur[j] = *(const short8*)&qkvw[((size_t)(nb * 8 + kbg) * 8 + cc) * 512
                                      + nn * 8];
    }
#pragma unroll
    for (int s = 0; s < 4; ++s) {
      if (s + 1 < 4) {
#pragma unroll
        for (int j = 0; j < 3; ++j) {
          int f = wave * 3 + j, region = f >> 2, sub = f & 3;
          int nb = region * 8 + h, nn = sub * 16 + l15;
          int kk = ch * 128 + (s + 1) * 32 + q * 8;
          int kbg = kk >> 6, cc = (kk & 63) >> 3;
          bnxt[j] = *(const short8*)&qkvw[((size_t)(nb * 8 + kbg) * 8 + cc) * 512
                                          + nn * 8];
        }
      }
      short8 af[5];
#pragma unroll
      for (int rt = 0; rt < 5; ++rt)
        af[rt] = *(short8*)&sta[(size_t)((s * 4 + q) * 80 + rt * 16 + l15) * 8];
#pragma unroll
      for (int rt = 0; rt < 5; ++rt)
#pragma unroll
        for (int j = 0; j < 3; ++j)
          acc[rt][j] = __builtin_amdgcn_mfma_f32_16x16x32_bf16(
              af[rt], bcur[j], acc[rt][j], 0, 0, 0);
#pragma unroll
      for (int j = 0; j < 3; ++j) bcur[j] = bnxt[j];
    }
  }

  // ---- write Q,K (fp32) and V (bf16) to LDS ----
#pragma unroll
  for (int rt = 0; rt < 5; ++rt) {
#pragma unroll
    for (int j = 0; j < 3; ++j) {
      int f = wave * 3 + j, region = f >> 2, sub = f & 3;
      int cw = sub * 16 + l15;
      float bias = qkvb[region * 512 + h * 64 + cw];
#pragma unroll
      for (int r = 0; r < 4; ++r) {
        int row = rt * 16 + q * 4 + r;
        if (row < 65) {
          float v = acc[rt][j][r] + bias;
          if      (region == 0) qf[row][cw] = v;
          else if (region == 1) kf[row][cw] = v;
          else                  vb[row][cw] = f2bf(v);
        }
      }
    }
  }
  __syncthreads();

  // ---- QK^T (289 4x4 tiles) ----
#pragma unroll
  for (int it = 0; it < 2; ++it) {
    int tile = it * 256 + tid;
    if (tile < 289) {
      int ti = (tile / 17) * 4, tj = (tile % 17) * 4;
      const float* qr[4]; const float* kr[4];
#pragma unroll
      for (int i = 0; i < 4; ++i) { qr[i] = qf[min(ti + i, 64)]; kr[i] = kf[min(tj + i, 64)]; }
      float a4[4][4] = {};
      for (int d = 0; d < 64; ++d) {
        float a[4], bvv[4];
#pragma unroll
        for (int i = 0; i < 4; ++i) { a[i] = qr[i][d]; bvv[i] = kr[i][d]; }
#pragma unroll
        for (int i = 0; i < 4; ++i)
#pragma unroll
          for (int j = 0; j < 4; ++j) a4[i][j] += a[i] * bvv[j];
      }
#pragma unroll
      for (int i = 0; i < 4; ++i)
        if (ti + i < 65)
#pragma unroll
          for (int j = 0; j < 4; ++j)
            if (tj + j < 65) ss[ti + i][tj + j] = a4[i][j] * 0.125f;
    }
  }
  __syncthreads();

  // ---- softmax rows ----
  if (tid < 65) {
    float mx = -1e30f;
    for (int j = 0; j < 65; ++j) mx = fmaxf(mx, ss[tid][j]);
    float s = 0.0f;
    for (int j = 0; j < 65; ++j) { float e = expf(ss[tid][j] - mx); ss[tid][j] = e; s += e; }
    float inv = 1.0f / s;
    for (int j = 0; j < 65; ++j) ss[tid][j] *= inv;
  }
  __syncthreads();

  // ---- PV (272 4x4 tiles), V from bf16 LDS ----
#pragma unroll
  for (int it = 0; it < 2; ++it) {
    int tile = it * 256 + tid;
    if (tile < 272) {
      int ti = (tile >> 4) * 4, d0 = (tile & 15) * 4;
      const float* sr[4];
#pragma unroll
      for (int i = 0; i < 4; ++i) sr[i] = ss[min(ti + i, 64)];
      float a4[4][4] = {};
      for (int j = 0; j < 65; ++j) {
        float v0 = bf2f(vb[j][d0]),   v1 = bf2f(vb[j][d0+1]);
        float v2 = bf2f(vb[j][d0+2]), v3 = bf2f(vb[j][d0+3]);
#pragma unroll
        for (int i = 0; i < 4; ++i) {
          float s = sr[i][j];
          a4[i][0] += s * v0; a4[i][1] += s * v1;
          a4[i][2] += s * v2; a4[i][3] += s * v3;
        }
      }
#pragma unroll
      for (int i = 0; i < 4; ++i)
        if (ti + i < 65) {
          ushort4 o;
          o.x = f2bf(a4[i][0]); o.y = f2bf(a4[i][1]);
          o.z = f2bf(a4[i][2]); o.w = f2bf(a4[i][3]);
          *(ushort4*)(obufb + pidx(b * NP1 + ti + i, h * 64 + d0, 8)) = o;
        }
    }
  }
}

// ---------------------------------------------------------------------------
// fused_row512: R15-proven. 8 waves (512 thr), 65 blocks, 16 rows x 512 cols,
// K=512. Wave owns 64 cols (4 frags); packed A (LDS) + B (L2, 2-deep).
// out-proj + out_b + residual -> LN1 -> xs (linear), xsb (packed)
// ---------------------------------------------------------------------------
__global__ __launch_bounds__(512) void fused_row512(
    const u16* __restrict__ A, const u16* __restrict__ Bw,
    const float* __restrict__ bias,
    float* __restrict__ xs, u16* __restrict__ xsb,
    const float* __restrict__ g, const float* __restrict__ bb)
{
  constexpr int KB = 8;
  __shared__ alignas(16) u16 Alds[16 * 512];     // 16 KB
  __shared__ float red[8][16];
  __shared__ float red2[8][16];
  const int tid = threadIdx.x, lane = tid & 63, wave = tid >> 6;
  const int l15 = lane & 15, q = lane >> 4;
  const int r0 = blockIdx.x * 16;
  const int rb = r0 >> 6, ro = r0 & 63;
  const int gc0 = wave * 64;
  const int nb = wave;

  f32x4 acc[4];
#pragma unroll
  for (int i = 0; i < 4; ++i) acc[i] = (f32x4){0,0,0,0};

  for (int idx = tid; idx < 1024; idx += 512) {
    int rloc = idx & 15, cg = idx >> 4;
    int kbg = cg >> 3, cc = cg & 7;
    async16(A + ((size_t)(rb * KB + kbg) * 8 + cc) * 512 + (ro + rloc) * 8,
            &Alds[(size_t)idx * 8]);
  }
  asm volatile("s_waitcnt vmcnt(0)" ::: "memory");
  __syncthreads();

  short8 bcur[4], bnxt[4];
  {
    int kk = q * 8;
    int kbg = kk >> 6, cc = (kk & 63) >> 3;
#pragma unroll
    for (int i = 0; i < 4; ++i)
      bcur[i] = *(const short8*)&Bw[((size_t)(nb * KB + kbg) * 8 + cc) * 512
                                    + (i * 16 + l15) * 8];
  }
  for (int s = 0; s < 16; ++s) {
    if (s + 1 < 16) {
      int kk = (s + 1) * 32 + q * 8;
      int kbg = kk >> 6, cc = (kk & 63) >> 3;
#pragma unroll
      for (int i = 0; i < 4; ++i)
        bnxt[i] = *(const short8*)&Bw[((size_t)(nb * KB + kbg) * 8 + cc) * 512
                                      + (i * 16 + l15) * 8];
    }
    short8 af = *(const short8*)&Alds[(size_t)((s * 4 + q) * 16 + l15) * 8];
#pragma unroll
    for (int i = 0; i < 4; ++i)
      acc[i] = __builtin_amdgcn_mfma_f32_16x16x32_bf16(af, bcur[i], acc[i], 0, 0, 0);
#pragma unroll
    for (int i = 0; i < 4; ++i) bcur[i] = bnxt[i];
  }

  float vv[4][4];
#pragma unroll
  for (int i = 0; i < 4; ++i) {
    int col = gc0 + i*16 + l15;
    float bcol = bias[col];
#pragma unroll
    for (int r = 0; r < 4; ++r) {
      int gr = r0 + q*4 + r;
      vv[i][r] = acc[i][r] + bcol + xs[(size_t)gr * Dm + col];
    }
  }
  float ps[4];
#pragma unroll
  for (int r = 0; r < 4; ++r) {
    float s = 0.f;
#pragma unroll
    for (int i = 0; i < 4; ++i) s += vv[i][r];
    ps[r] = s;
  }
#pragma unroll
  for (int o = 1; o < 16; o <<= 1)
#pragma unroll
    for (int r = 0; r < 4; ++r) ps[r] += __shfl_xor(ps[r], o, 64);
  if (l15 == 0)
#pragma unroll
    for (int r = 0; r < 4; ++r) red[wave][q*4 + r] = ps[r];
  __syncthreads();
  float mu[4];
#pragma unroll
  for (int r = 0; r < 4; ++r) {
    int rr = q*4 + r;
    float s = 0.f;
#pragma unroll
    for (int w = 0; w < 8; ++w) s += red[w][rr];
    mu[r] = s * (1.0f/512.0f);
  }
  float ps2[4];
#pragma unroll
  for (int r = 0; r < 4; ++r) {
    float s = 0.f;
#pragma unroll
    for (int i = 0; i < 4; ++i) { float d = vv[i][r] - mu[r]; s += d * d; }
    ps2[r] = s;
  }
#pragma unroll
  for (int o = 1; o < 16; o <<= 1)
#pragma unroll
    for (int r = 0; r < 4; ++r) ps2[r] += __shfl_xor(ps2[r], o, 64);
  if (l15 == 0)
#pragma unroll
    for (int r = 0; r < 4; ++r) red2[wave][q*4 + r] = ps2[r];
  __syncthreads();
  float inv[4];
#pragma unroll
  for (int r = 0; r < 4; ++r) {
    int rr = q*4 + r;
    float s = 0.f;
#pragma unroll
    for (int w = 0; w < 8; ++w) s += red2[w][rr];
    inv[r] = rsqrtf(s * (1.0f/512.0f) + 1e-5f);
  }
#pragma unroll
  for (int i = 0; i < 4; ++i) {
    int col = gc0 + i*16 + l15;
    float gc = g[col], bc = bb[col];
#pragma unroll
    for (int r = 0; r < 4; ++r) {
      int gr = r0 + q*4 + r;
      float y = (vv[i][r] - mu[r]) * inv[r] * gc + bc;
      xs[(size_t)gr * Dm + col] = y;
      xsb[pidx(gr, col, 8)] = f2bf(y);
    }
  }
}

// ---------------------------------------------------------------------------
// fused_ffx<HEAD>: 65 blocks x 16 waves (1024 thr), 16 rows. ff1 (+b1,gelu)
// with H in LDS in two 1024-col chunks; ff2 accumulates K-ascending across
// chunks (bit-identical to split path); +b2 +residual -> LN2.
// All global streams 2-deep register-prefetched. LDS: A1 16KB + H 32KB.
// HEAD=0: write xs/xsb. HEAD=1 (last layer): y -> A1 (packed-A), u/h head
// GEMM (K=512) + closed-form projection in-block (R19-proven epilogue).
// ---------------------------------------------------------------------------
template<int HEAD>
__global__ __launch_bounds__(1024) void fused_ffx(
    const u16* __restrict__ xsb_in, const u16* __restrict__ f1w,
    const u16* __restrict__ f2w, const float* __restrict__ b1,
    const float* __restrict__ b2,
    float* __restrict__ xs, u16* __restrict__ xsb,
    const float* __restrict__ g, const float* __restrict__ bb,
    const u16* __restrict__ uhw, const float* __restrict__ ub,
    const float* __restrict__ hbv, const float* __restrict__ marg,
    const float* __restrict__ xg, float* __restrict__ outu,
    float* __restrict__ outh)
{
  __shared__ alignas(16) u16 A1[16 * 512];       // 16 KB packed-A (K=512)
  __shared__ alignas(16) u16 H[16 * 1024];       // 32 KB packed-A (K-chunk)
  __shared__ float red[16][16];
  __shared__ float red2[16][16];
  const int tid = threadIdx.x, lane = tid & 63, wave = tid >> 6;  // 0..15
  const int l15 = lane & 15, q = lane >> 4;
  const int r0 = blockIdx.x * 16;
  const int rb = r0 >> 6, ro = r0 & 63;

  // ---- stage A1: 16 rows x 512 from packed xsb (1 async16/thread) ----
  {
    int idx = tid;
    int rloc = idx & 15, cg = idx >> 4;          // cg 0..63
    int kbg = cg >> 3, cc = cg & 7;
    async16(xsb_in + ((size_t)(rb * 8 + kbg) * 8 + cc) * 512 + (ro + rloc) * 8,
            &A1[(size_t)idx * 8]);
  }
  asm volatile("s_waitcnt vmcnt(0)" ::: "memory");
  __syncthreads();

  f32x4 acc2[2];
  acc2[0] = (f32x4){0,0,0,0}; acc2[1] = (f32x4){0,0,0,0};
  const int nb2 = wave >> 1;                     // ff2 out 64-col block 0..7
  const int nn2 = (wave & 1) * 32;

  for (int ch = 0; ch < 2; ++ch) {
    // ---- ff1 chunk: cols [ch*1024, +1024); wave owns 64 cols (4 frags) ----
    const int fcol0 = ch * 1024 + wave * 64;
    const int fnb = fcol0 >> 6;                  // f1w n-block (KB=8)
    f32x4 acc1[4];
#pragma unroll
    for (int i = 0; i < 4; ++i) acc1[i] = (f32x4){0,0,0,0};
    short8 bcur[4], bnxt[4];
    {
      int kk = q * 8;
      int kbg = kk >> 6, cc = (kk & 63) >> 3;
#pragma unroll
      for (int i = 0; i < 4; ++i)
        bcur[i] = *(const short8*)&f1w[((size_t)(fnb * 8 + kbg) * 8 + cc) * 512
                                       + (i * 16 + l15) * 8];
    }
    for (int s = 0; s < 16; ++s) {
      if (s + 1 < 16) {
        int kk = (s + 1) * 32 + q * 8;
        int kbg = kk >> 6, cc = (kk & 63) >> 3;
#pragma unroll
        for (int i = 0; i < 4; ++i)
          bnxt[i] = *(const short8*)&f1w[((size_t)(fnb * 8 + kbg) * 8 + cc) * 512
                                         + (i * 16 + l15) * 8];
      }
      short8 af = *(const short8*)&A1[(size_t)((s * 4 + q) * 16 + l15) * 8];
#pragma unroll
      for (int i = 0; i < 4; ++i)
        acc1[i] = __builtin_amdgcn_mfma_f32_16x16x32_bf16(af, bcur[i], acc1[i], 0, 0, 0);
#pragma unroll
      for (int i = 0; i < 4; ++i) bcur[i] = bnxt[i];
    }
    __syncthreads();     // prior ff2-phase reads of H done (no-op at ch=0)
    // gelu -> H (packed-A layout; local col lc in [0,1024))
#pragma unroll
    for (int i = 0; i < 4; ++i) {
      int lc = wave * 64 + i * 16 + l15;
      float bcol = b1[fcol0 + i * 16 + l15];
#pragma unroll
      for (int r = 0; r < 4; ++r) {
        int row = q * 4 + r;
        H[(size_t)((lc >> 3) * 16 + row) * 8 + (lc & 7)] =
            f2bf(gelu_exact(acc1[i][r] + bcol));
      }
    }
    __syncthreads();

    // ---- ff2 partial: K in [ch*1024, +1024) from H; wave owns 32 cols ----
    short8 c2[2], n2[2];
    {
      int kk = ch * 1024 + q * 8;
      int kbg = kk >> 6, cc = (kk & 63) >> 3;
#pragma unroll
      for (int i = 0; i < 2; ++i)
        c2[i] = *(const short8*)&f2w[((size_t)(nb2 * 32 + kbg) * 8 + cc) * 512
                                     + (nn2 + i * 16 + l15) * 8];
    }
    for (int s = 0; s < 32; ++s) {
      if (s + 1 < 32) {
        int kk = ch * 1024 + (s + 1) * 32 + q * 8;
        int kbg = kk >> 6, cc = (kk & 63) >> 3;
#pragma unroll
        for (int i = 0; i < 2; ++i)
          n2[i] = *(const short8*)&f2w[((size_t)(nb2 * 32 + kbg) * 8 + cc) * 512
                                       + (nn2 + i * 16 + l15) * 8];
      }
      short8 af = *(const short8*)&H[(size_t)((s * 4 + q) * 16 + l15) * 8];
#pragma unroll
      for (int i = 0; i < 2; ++i)
        acc2[i] = __builtin_amdgcn_mfma_f32_16x16x32_bf16(af, c2[i], acc2[i], 0, 0, 0);
#pragma unroll
      for (int i = 0; i < 2; ++i) c2[i] = n2[i];
    }
  }

  // ---- +b2 +residual -> LN2 (16-wave reduction, R19-proven) ----
  float vv[2][4];
#pragma unroll
  for (int i = 0; i < 2; ++i) {
    int col = wave * 32 + i*16 + l15;
    float bcol = b2[col];
#pragma unroll
    for (int r = 0; r < 4; ++r) {
      int gr = r0 + q*4 + r;
      vv[i][r] = acc2[i][r] + bcol + xs[(size_t)gr * Dm + col];
    }
  }
  float ps[4];
#pragma unroll
  for (int r = 0; r < 4; ++r) { ps[r] = vv[0][r] + vv[1][r]; }
#pragma unroll
  for (int o = 1; o < 16; o <<= 1)
#pragma unroll
    for (int r = 0; r < 4; ++r) ps[r] += __shfl_xor(ps[r], o, 64);
  if (l15 == 0)
#pragma unroll
    for (int r = 0; r < 4; ++r) red[wave][q*4 + r] = ps[r];
  __syncthreads();
  float mu[4];
#pragma unroll
  for (int r = 0; r < 4; ++r) {
    int rr = q*4 + r;
    float s = 0.f;
#pragma unroll
    for (int w = 0; w < 16; ++w) s += red[w][rr];
    mu[r] = s * (1.0f/512.0f);
  }
  float ps2[4];
#pragma unroll
  for (int r = 0; r < 4; ++r) {
    float d0 = vv[0][r] - mu[r], d1 = vv[1][r] - mu[r];
    ps2[r] = d0*d0 + d1*d1;
  }
#pragma unroll
  for (int o = 1; o < 16; o <<= 1)
#pragma unroll
    for (int r = 0; r < 4; ++r) ps2[r] += __shfl_xor(ps2[r], o, 64);
  if (l15 == 0)
#pragma unroll
    for (int r = 0; r < 4; ++r) red2[wave][q*4 + r] = ps2[r];
  __syncthreads();
  float inv[4];
#pragma unroll
  for (int r = 0; r < 4; ++r) {
    int rr = q*4 + r;
    float s = 0.f;
#pragma unroll
    for (int w = 0; w < 16; ++w) s += red2[w][rr];
    inv[r] = rsqrtf(s * (1.0f/512.0f) + 1e-5f);
  }

  if (HEAD == 0) {
#pragma unroll
    for (int i = 0; i < 2; ++i) {
      int col = wave * 32 + i*16 + l15;
      float gc = g[col], bc = bb[col];
#pragma unroll
      for (int r = 0; r < 4; ++r) {
        int gr = r0 + q*4 + r;
        float y = (vv[i][r] - mu[r]) * inv[r] * gc + bc;
        xs[(size_t)gr * Dm + col] = y;
        xsb[pidx(gr, col, 8)] = f2bf(y);
      }
    }
  } else {
    // ---- y (bf16) -> A1 packed-A (col<512 => fits 16 KB) ----
    __syncthreads();
#pragma unroll
    for (int i = 0; i < 2; ++i) {
      int col = wave * 32 + i*16 + l15;
      float gc = g[col], bc = bb[col];
#pragma unroll
      for (int r = 0; r < 4; ++r) {
        float y = (vv[i][r] - mu[r]) * inv[r] * gc + bc;
        A1[(size_t)((col >> 3) * 16 + (q*4 + r)) * 8 + (col & 7)] = f2bf(y);
      }
    }
    __syncthreads();

    // ---- head GEMM: K=512, 16 steps; wave owns 32 head cols ----
    const int w2 = (wave < 8) ? wave : (wave - 8);
    const int ubr = ((wave < 8) ? 0 : 4) + (w2 >> 1);   // uh 64-row block
    const int hn0 = (w2 & 1) * 32;
    f32x4 a2[2];
    a2[0] = (f32x4){0,0,0,0}; a2[1] = (f32x4){0,0,0,0};
    short8 hc[2], hn[2];
    {
      int kk = q * 8;
      int kbg = kk >> 6, cc = (kk & 63) >> 3;
#pragma unroll
      for (int i = 0; i < 2; ++i)
        hc[i] = *(const short8*)&uhw[((size_t)(ubr * 8 + kbg) * 8 + cc) * 512
                                     + (hn0 + i * 16 + l15) * 8];
    }
    for (int s = 0; s < 16; ++s) {
      if (s + 1 < 16) {
        int kk = (s + 1) * 32 + q * 8;
        int kbg = kk >> 6, cc = (kk & 63) >> 3;
#pragma unroll
        for (int i = 0; i < 2; ++i)
          hn[i] = *(const short8*)&uhw[((size_t)(ubr * 8 + kbg) * 8 + cc) * 512
                                       + (hn0 + i * 16 + l15) * 8];
      }
      short8 af = *(const short8*)&A1[(size_t)((s * 4 + q) * 16 + l15) * 8];
#pragma unroll
      for (int i = 0; i < 2; ++i)
        a2[i] = __builtin_amdgcn_mfma_f32_16x16x32_bf16(af, hc[i], a2[i], 0, 0, 0);
#pragma unroll
      for (int i = 0; i < 2; ++i) hc[i] = hn[i];
    }

    // ---- projection reduction (h waves) + uniform barrier + writes ----
    float va[2][4];
    if (wave >= 8) {
      float wd[4] = {0.f,0.f,0.f,0.f}, ms[4] = {0.f,0.f,0.f,0.f};
#pragma unroll
      for (int i = 0; i < 2; ++i) {
        int hcol = (wave - 8) * 32 + i*16 + l15;
        float bcol = hbv[hcol];
        float xv = xg[hcol];
#pragma unroll
        for (int r = 0; r < 4; ++r) {
          int gr = r0 + q*4 + r;
          float a = a2[i][r] + bcol;
          va[i][r] = a;
          float uvm = marg[(size_t)gr * MG + hcol];
          wd[r] += uvm * (f_closed(a) - xv);
          ms[r] += uvm;
        }
      }
#pragma unroll
      for (int o = 1; o < 16; o <<= 1)
#pragma unroll
        for (int r = 0; r < 4; ++r) {
          wd[r] += __shfl_xor(wd[r], o, 64);
          ms[r] += __shfl_xor(ms[r], o, 64);
        }
      if (l15 == 0)
#pragma unroll
        for (int r = 0; r < 4; ++r) {
          red[wave][q*4 + r]  = wd[r];
          red2[wave][q*4 + r] = ms[r];
        }
    }
    __syncthreads();
    if (wave < 8) {
#pragma unroll
      for (int i = 0; i < 2; ++i) {
        int col = wave * 32 + i*16 + l15;
        float bcol = ub[col];
#pragma unroll
        for (int r = 0; r < 4; ++r) {
          int gr = r0 + q*4 + r;
          outu[(size_t)gr * MG + col] = a2[i][r] + bcol;
        }
      }
    } else {
#pragma unroll
      for (int i = 0; i < 2; ++i) {
        int hcol = (wave - 8) * 32 + i*16 + l15;
#pragma unroll
        for (int r = 0; r < 4; ++r) {
          int rr = q*4 + r;
          int gr = r0 + rr;
          int bI = gr / NP1, n = gr - bI * NP1;
          if (n < 64) {
            float num = 0.f, den = 0.f;
#pragma unroll
            for (int w = 8; w < 16; ++w) { num += red[w][rr]; den += red2[w][rr]; }
            float corr = num / (den + 1e-8f);
            outh[(size_t)(bI * 64 + n) * MG + hcol] = va[i][r] - corr;
          }
        }
      }
    }
  }
}

// ---------------------------------------------------------------------------
extern "C" void kernel_launch(void* const* d_in, const int* in_sizes, int n_in,
                              void* d_out, int out_size, void* d_ws, size_t ws_size,
                              hipStream_t stream)
{
  const float* marg   = (const float*)d_in[0];
  const float* xg     = (const float*)d_in[1];
  const float* conv_w = (const float*)d_in[2];
  const float* conv_b = (const float*)d_in[3];
  const float* fc_w   = (const float*)d_in[4];
  const float* fc_b   = (const float*)d_in[5];
  const float* ln0_g  = (const float*)d_in[6];
  const float* ln0_b  = (const float*)d_in[7];
  const float* pos    = (const float*)d_in[8];
  const float* qkv_w  = (const float*)d_in[9];
  const float* qkv_b  = (const float*)d_in[10];
  const float* out_w  = (const float*)d_in[11];
  const float* out_b  = (const float*)d_in[12];
  const float* ln1_g  = (const float*)d_in[13];
  const float* ln1_b  = (const float*)d_in[14];
  const float* ff1_w  = (const float*)d_in[15];
  const float* ff1_b  = (const float*)d_in[16];
  const float* ff2_w  = (const float*)d_in[17];
  const float* ff2_b  = (const float*)d_in[18];
  const float* ln2_g  = (const float*)d_in[19];
  const float* ln2_b  = (const float*)d_in[20];
  const float* u_w    = (const float*)d_in[21];
  const float* u_b    = (const float*)d_in[22];
  const float* h_w    = (const float*)d_in[23];
  const float* h_b    = (const float*)d_in[24];
  float* out = (float*)d_out;

  float* ws = (float*)d_ws;
  float* xs      = ws;                              // 532480 f32 (linear)
  u16*   xsb     = (u16*)(ws + 2129920);            // 1088x512 packed
  u16*   obufb   = (u16*)(ws + 2408448);            // 1088x512 packed
  u16*   wbf     = (u16*)(ws + 3801088);            // 9699328 u16 packed

  const u16* qkv_bw = wbf;
  const u16* out_bw = wbf + 2359296;
  const u16* ff1_bw = wbf + 3145728;
  const u16* ff2_bw = wbf + 6291456;
  const u16* uh_bw  = wbf + 9437184;   // u rows 0..255, h rows 256..511

  prep_kernel<<<772, 256, 0, stream>>>(
      qkv_w, out_w, ff1_w, ff2_w, u_w, h_w, wbf,
      marg, conv_w, conv_b, fc_w, fc_b, ln0_g, ln0_b, pos, xs, xsb);

  for (int l = 0; l < 3; ++l) {
    fused_qkv_attn<<<128, 256, 0, stream>>>(
        xsb, qkv_bw + (size_t)l*786432, qkv_b + l*1536, obufb);
    fused_row512<<<65, 512, 0, stream>>>(
        obufb, out_bw + (size_t)l*262144, out_b + l*512,
        xs, xsb, ln1_g + l*512, ln1_b + l*512);
    if (l < 2) {
      fused_ffx<0><<<65, 1024, 0, stream>>>(
          xsb, ff1_bw + (size_t)l*1048576, ff2_bw + (size_t)l*1048576,
          ff1_b + l*2048, ff2_b + l*512,
          xs, xsb, ln2_g + l*512, ln2_b + l*512,
          nullptr, nullptr, nullptr, nullptr, nullptr, nullptr, nullptr);
    } else {
      fused_ffx<1><<<65, 1024, 0, stream>>>(
          xsb, ff1_bw + (size_t)l*1048576, ff2_bw + (size_t)l*1048576,
          ff1_b + l*2048, ff2_b + l*512,
          xs, xsb, ln2_g + l*512, ln2_b + l*512,
          uh_bw, u_b, h_b, marg, xg, out, out + 1040*256);
    }
  }
}

// Round 13
// 378.840 us; speedup vs baseline: 1.0956x; 1.0956x over previous
//
#include <hip/hip_runtime.h>
#include <math.h>

// ---------------------------------------------------------------------------
// B=16, NP1=65, BT=1040, Mg=256, D=512, H=8, DH=64, L=3, DFF=2048
// R21: exact revert to R15 (379.3us, session best). Ledger of subsequent
// attempts: R16 8-row fused_row +6us; R17 fused_ff +255us; R18 4-deep ring
// +24us; R19 16-wave ff2 + head-merge +2us; R20 fused_ffx +34us. Remaining
// time is ~14us/boundary x 13 boundaries + latency-bound interiors that
// resisted prefetch-depth/TLP/fusion levers in both directions; grid-sync
// megakernel measured 30-40us/sync (worse). 14 dispatches.
//  - prep: weight fp32->bf16 MFMA-chunk packing + embed pipeline
//  - fused_qkv_attn: per-(b,h) QKV MFMA + in-block attention
//  - fused_row<512,0>: out-proj + residual + LN1 (65 blk x 8 waves)
//  - gemm_mfma<1>: ff1 + GELU (544 blocks, packed)
//  - fused_row<2048,0>: ff2 + residual + LN2
//  - fused_row<512,1>: u/h head + closed-form projection
// ---------------------------------------------------------------------------

#define BT   1040
#define NP1  65
#define Dm   512
#define MG   256

typedef short short8 __attribute__((ext_vector_type(8)));
typedef float f32x4  __attribute__((ext_vector_type(4)));
typedef unsigned short u16;

// packed u16 index of element (r, c) in a [R][C] bf16 matrix, KB = C/64
__device__ __forceinline__ size_t pidx(int r, int c, int KB) {
  return ((size_t)((r >> 6) * KB + (c >> 6)) * 8 + ((c & 63) >> 3)) * 512
       + (size_t)((r & 63) * 8 + (c & 7));
}

__device__ __forceinline__ u16 f2bf(float f) {
  unsigned int u = __float_as_uint(f);
  u += 0x7FFF + ((u >> 16) & 1);          // RNE
  return (u16)(u >> 16);
}

__device__ __forceinline__ float bf2f(u16 v) {
  return __uint_as_float((unsigned int)v << 16);
}

__device__ __forceinline__ float gelu_exact(float x) {
  return 0.5f * x * (1.0f + erff(x * 0.70710678118654752f));
}

__device__ __forceinline__ void async16(const u16* g, u16* l) {
  __builtin_amdgcn_global_load_lds(
      (const __attribute__((address_space(1))) unsigned int*)g,
      (__attribute__((address_space(3))) unsigned int*)l, 16, 0, 0);
}

__device__ __forceinline__ float wred(float v) {
#pragma unroll
  for (int o = 32; o; o >>= 1) v += __shfl_xor(v, o, 64);
  return v;
}

__device__ __forceinline__ float block_reduce_sum(float v, float* s) {
#pragma unroll
  for (int off = 32; off; off >>= 1) v += __shfl_down(v, off, 64);
  int lane = threadIdx.x & 63, wid = threadIdx.x >> 6;
  __syncthreads();
  if (lane == 0) s[wid] = v;
  __syncthreads();
  return s[0] + s[1] + s[2] + s[3];
}

// closed-form expected grid value under weights exp(-a*x_j/eps), x_j uniform:
__device__ __forceinline__ float f_closed(float a) {
  const float tf = 2.3529411765f;     // (6/255)*100
  float t = a * tf;
  float s = fabsf(t);
  float E;
  if (s < 1e-4f) {
    E = 127.5f - 5461.25f * t;        // series; kappa2=(256^2-1)/12
  } else {
    float u = s * 256.0f;
    float term2 = (u < 80.0f) ? 256.0f / expm1f(u) : 0.0f;
    float Epos = 1.0f / expm1f(s) - term2;
    E = (t > 0.0f) ? Epos : 255.0f - Epos;
  }
  return -3.0f + 0.0235294118f * E;   // delta = 6/255
}

// ---------------------------------------------------------------------------
// prep: blocks [0,512) convert+PACK weights fp32->bf16; [512,772) embed
// ---------------------------------------------------------------------------
__global__ __launch_bounds__(256) void prep_kernel(
    const float* __restrict__ qkv_w, const float* __restrict__ out_w,
    const float* __restrict__ ff1_w, const float* __restrict__ ff2_w,
    const float* __restrict__ u_w,   const float* __restrict__ h_w,
    u16* __restrict__ wdst,
    const float* __restrict__ marg, const float* __restrict__ conv_w,
    const float* __restrict__ conv_b, const float* __restrict__ fc_w,
    const float* __restrict__ fc_b, const float* __restrict__ g,
    const float* __restrict__ bb, const float* __restrict__ pos,
    float* __restrict__ xs, u16* __restrict__ xsb)
{
  const int tid = threadIdx.x;
  if (blockIdx.x < 512) {
    const size_t O1 = 2359296, O2 = 3145728, O3 = 6291456;
    const size_t O4 = 9437184, O5 = 9568256, TOT4 = 9699328 / 4;
    for (size_t e4 = (size_t)blockIdx.x * 256 + tid; e4 < TOT4;
         e4 += (size_t)512 * 256) {
      size_t e = e4 * 4;
      const float* src; size_t base; int n, k, KB;
      if (e < O1)      { size_t r = e;      src = qkv_w + r; base = 0;
                         n = (int)(r >> 9);  k = (int)(r & 511);  KB = 8; }
      else if (e < O2) { size_t r = e - O1; src = out_w + r; base = O1;
                         n = (int)(r >> 9);  k = (int)(r & 511);  KB = 8; }
      else if (e < O3) { size_t r = e - O2; src = ff1_w + r; base = O2;
                         n = (int)(r >> 9);  k = (int)(r & 511);  KB = 8; }
      else if (e < O4) { size_t r = e - O3; src = ff2_w + r; base = O3;
                         n = (int)(r >> 11); k = (int)(r & 2047); KB = 32; }
      else if (e < O5) { size_t r = e - O4; src = u_w + r;   base = O4;
                         n = (int)(r >> 9);  k = (int)(r & 511);  KB = 8; }
      else             { size_t r = e - O5; src = h_w + r;   base = O4;
                         n = 256 + (int)(r >> 9); k = (int)(r & 511); KB = 8; }
      float4 v = *(const float4*)src;
      unsigned int lo = (unsigned int)f2bf(v.x) | ((unsigned int)f2bf(v.y) << 16);
      unsigned int hi = (unsigned int)f2bf(v.z) | ((unsigned int)f2bf(v.w) << 16);
      *(uint2*)(wdst + base + pidx(n, k, KB)) = make_uint2(lo, hi);
    }
    return;
  }
  // ---- embed: 4 tokens per block ----
  __shared__ float es[4][128];
  __shared__ float sS[4];
  __shared__ float edge[4][4];
  __shared__ float red[4];
  const int t0 = (blockIdx.x - 512) * 4;
  const int lane = tid & 63, wave = tid >> 6;
  {
    float4 mv = *(const float4*)(marg + (size_t)(t0 + wave) * MG + lane * 4);
    float S = wred(mv.x + mv.y + mv.z + mv.w);
    if (lane == 0) sS[wave] = S;
  }
  if (tid < 16) {
    int k = tid >> 2, e = tid & 3;
    int idx = (e < 2) ? e : (e + 252);       // 0,1,254,255
    edge[k][e] = marg[(size_t)(t0 + k) * MG + idx];
  }
  __syncthreads();
  if (tid < 128) {
    int o = tid;
    float w0 = conv_w[o*5+0], w1 = conv_w[o*5+1], w2 = conv_w[o*5+2];
    float w3 = conv_w[o*5+3], w4 = conv_w[o*5+4], cb = conv_b[o];
#pragma unroll
    for (int k = 0; k < 4; ++k) {
      float S = sS[k];
      float x0 = edge[k][0], x1 = edge[k][1], x254 = edge[k][2], x255 = edge[k][3];
      es[k][o] = (w0*(S - x254 - x255) + w1*(S - x255) + w2*S
                + w3*(S - x0) + w4*(S - x0 - x1)) * (1.0f/256.0f) + cb;
    }
  }
  __syncthreads();
  float b0 = fc_b[tid], b1 = fc_b[tid + 256];
  float z[4][2];
#pragma unroll
  for (int k = 0; k < 4; ++k) { z[k][0] = b0; z[k][1] = b1; }
#pragma unroll 4
  for (int o = 0; o < 128; ++o) {
    float f0 = fc_w[(size_t)o*Dm + tid];
    float f1 = fc_w[(size_t)o*Dm + tid + 256];
#pragma unroll
    for (int k = 0; k < 4; ++k) {
      float e = es[k][o];
      z[k][0] += e * f0; z[k][1] += e * f1;
    }
  }
  float g0 = g[tid], g1 = g[tid+256], e0 = bb[tid], e1 = bb[tid+256];
#pragma unroll
  for (int k = 0; k < 4; ++k) {
    float mu = block_reduce_sum(z[k][0] + z[k][1], red) * (1.0f/512.0f);
    float d0 = z[k][0] - mu, d1 = z[k][1] - mu;
    float var = block_reduce_sum(d0*d0 + d1*d1, red) * (1.0f/512.0f);
    float inv = rsqrtf(var + 1e-5f);
    int t = t0 + k, p = t % NP1;
    float y0 = gelu_exact(d0*inv*g0 + e0) + pos[(size_t)p*Dm + tid];
    float y1 = gelu_exact(d1*inv*g1 + e1) + pos[(size_t)p*Dm + tid + 256];
    xs[(size_t)t*Dm + tid]        = y0;
    xs[(size_t)t*Dm + tid + 256]  = y1;
    xsb[pidx(t, tid, 8)]          = f2bf(y0);
    xsb[pidx(t, tid + 256, 8)]    = f2bf(y1);
  }
}

// ---------------------------------------------------------------------------
// 64x64 MFMA tile GEMM (ff1 only), packed A/B, async16 dbuf, 4 waves 2x2.
// MODE 1: bf16 gelu(v+bias) -> PACKED Cb (KB=32)
// ---------------------------------------------------------------------------
template<int MODE>
__global__ __launch_bounds__(256) void gemm_mfma(
    const u16* __restrict__ A, const u16* __restrict__ Bw,
    const float* __restrict__ bias, float* __restrict__ Cf,
    u16* __restrict__ Cb, int Mrows, int N, int K)
{
  __shared__ alignas(16) u16 Asl[2][4096];
  __shared__ alignas(16) u16 Bsl[2][4096];
  const int tid = threadIdx.x;
  const int row0 = blockIdx.y * 64, col0 = blockIdx.x * 64;
  const int lane = tid & 63, wave = tid >> 6;
  const int wm = (wave >> 1) * 32, wn = (wave & 1) * 32;
  const int l15 = lane & 15, q = lane >> 4;
  const int KB = K >> 6;

  f32x4 acc[2][2];
  acc[0][0] = (f32x4){0,0,0,0}; acc[0][1] = (f32x4){0,0,0,0};
  acc[1][0] = (f32x4){0,0,0,0}; acc[1][1] = (f32x4){0,0,0,0};

  const size_t abase = (size_t)blockIdx.y * KB * 4096 + (size_t)lane * 8;
  const size_t bbase = (size_t)blockIdx.x * KB * 4096 + (size_t)lane * 8;
  const int c0w = wave * 2;

#pragma unroll
  for (int i = 0; i < 2; ++i) {
    int c = c0w + i;
    async16(A + abase + (size_t)c * 512, &Asl[0][(size_t)(c * 64 + lane) * 8]);
    async16(Bw + bbase + (size_t)c * 512, &Bsl[0][(size_t)(c * 64 + lane) * 8]);
  }

  const int nk = K >> 6;
  for (int t = 0; t < nk; ++t) {
    const int cur = t & 1;
    if (t + 1 < nk) {
      const int nxt = cur ^ 1;
#pragma unroll
      for (int i = 0; i < 2; ++i) {
        int c = c0w + i;
        async16(A + abase + (size_t)((t + 1) * 8 + c) * 512,
                &Asl[nxt][(size_t)(c * 64 + lane) * 8]);
        async16(Bw + bbase + (size_t)((t + 1) * 8 + c) * 512,
                &Bsl[nxt][(size_t)(c * 64 + lane) * 8]);
      }
      asm volatile("s_waitcnt vmcnt(4)" ::: "memory");
    } else {
      asm volatile("s_waitcnt vmcnt(0)" ::: "memory");
    }
    __builtin_amdgcn_s_barrier();
#pragma unroll
    for (int tt = 0; tt < 2; ++tt) {
      int cc = tt * 4 + q;
      short8 af[2], bf[2];
#pragma unroll
      for (int mi = 0; mi < 2; ++mi)
        af[mi] = *(short8*)&Asl[cur][(size_t)(cc*64 + wm + mi*16 + l15) * 8];
#pragma unroll
      for (int ni = 0; ni < 2; ++ni)
        bf[ni] = *(short8*)&Bsl[cur][(size_t)(cc*64 + wn + ni*16 + l15) * 8];
#pragma unroll
      for (int mi = 0; mi < 2; ++mi)
#pragma unroll
        for (int ni = 0; ni < 2; ++ni)
          acc[mi][ni] = __builtin_amdgcn_mfma_f32_16x16x32_bf16(
              af[mi], bf[ni], acc[mi][ni], 0, 0, 0);
    }
    __builtin_amdgcn_s_barrier();
  }

#pragma unroll
  for (int mi = 0; mi < 2; ++mi) {
#pragma unroll
    for (int ni = 0; ni < 2; ++ni) {
      int col = col0 + wn + ni*16 + l15;
#pragma unroll
      for (int r = 0; r < 4; ++r) {
        int row = row0 + wm + mi*16 + q*4 + r;
        if (row < Mrows) {
          float v = acc[mi][ni][r];
          if (MODE == 0) {
            Cf[(size_t)row*N + col] = v + bias[col];
          } else {
            Cb[pidx(row, col, 32)] = f2bf(gelu_exact(v + bias[col]));
          }
        }
      }
    }
  }
}

// ---------------------------------------------------------------------------
// fused_qkv_attn: one block per (b,h). MFMA computes Q,K,V (65x192, K=512)
// from packed xsb / qkv_w. Q,K fp32 LDS; V bf16 LDS; scores alias the A-stage
// buffer (flat u16 buf + casts). obufb packed.
// ---------------------------------------------------------------------------
__global__ __launch_bounds__(256) void fused_qkv_attn(
    const u16* __restrict__ xsb, const u16* __restrict__ qkvw,
    const float* __restrict__ qkvb, u16* __restrict__ obufb)
{
  __shared__ alignas(16) u16 stbuf[10240];       // 20480 B: A-stage | scores
  __shared__ alignas(16) float qf[65][67];
  __shared__ alignas(16) float kf[65][67];
  __shared__ alignas(16) u16   vb[65][68];
  u16* sta = stbuf;                              // [kg 16][row 80][8]
  float (*ss)[67] = (float (*)[67])stbuf;        // [65][67] = 17420 B, fits

  const int b = blockIdx.x >> 3, h = blockIdx.x & 7;
  const int tid = threadIdx.x, lane = tid & 63, wave = tid >> 6;
  const int l15 = lane & 15, q = lane >> 4;
  const int rowg0 = b * NP1;

  f32x4 acc[5][3];
#pragma unroll
  for (int rt = 0; rt < 5; ++rt)
#pragma unroll
    for (int j = 0; j < 3; ++j) acc[rt][j] = (f32x4){0,0,0,0};

  // ---- GEMM: K=512 in 4 chunks of 128 ----
  for (int ch = 0; ch < 4; ++ch) {
    __syncthreads();
    for (int idx = tid; idx < 16 * 80; idx += 256) {
      int kg = idx / 80, rl = idx - kg * 80;
      int r = rowg0 + min(rl, 64);
      async16(xsb + pidx(r, ch * 128 + kg * 8, 8), &sta[(size_t)idx * 8]);
    }
    asm volatile("s_waitcnt vmcnt(0)" ::: "memory");
    __syncthreads();

    short8 bcur[3], bnxt[3];
#pragma unroll
    for (int j = 0; j < 3; ++j) {
      int f = wave * 3 + j, region = f >> 2, sub = f & 3;
      int nb = region * 8 + h, nn = sub * 16 + l15;
      int kk = ch * 128 + q * 8;
      int kbg = kk >> 6, cc = (kk & 63) >> 3;
      bcur[j] = *(const short8*)&qkvw[((size_t)(nb * 8 + kbg) * 8 + cc) * 512
                                      + nn * 8];
    }
#pragma unroll
    for (int s = 0; s < 4; ++s) {
      if (s + 1 < 4) {
#pragma unroll
        for (int j = 0; j < 3; ++j) {
          int f = wave * 3 + j, region = f >> 2, sub = f & 3;
          int nb = region * 8 + h, nn = sub * 16 + l15;
          int kk = ch * 128 + (s + 1) * 32 + q * 8;
          int kbg = kk >> 6, cc = (kk & 63) >> 3;
          bnxt[j] = *(const short8*)&qkvw[((size_t)(nb * 8 + kbg) * 8 + cc) * 512
                                          + nn * 8];
        }
      }
      short8 af[5];
#pragma unroll
      for (int rt = 0; rt < 5; ++rt)
        af[rt] = *(short8*)&sta[(size_t)((s * 4 + q) * 80 + rt * 16 + l15) * 8];
#pragma unroll
      for (int rt = 0; rt < 5; ++rt)
#pragma unroll
        for (int j = 0; j < 3; ++j)
          acc[rt][j] = __builtin_amdgcn_mfma_f32_16x16x32_bf16(
              af[rt], bcur[j], acc[rt][j], 0, 0, 0);
#pragma unroll
      for (int j = 0; j < 3; ++j) bcur[j] = bnxt[j];
    }
  }

  // ---- write Q,K (fp32) and V (bf16) to LDS ----
#pragma unroll
  for (int rt = 0; rt < 5; ++rt) {
#pragma unroll
    for (int j = 0; j < 3; ++j) {
      int f = wave * 3 + j, region = f >> 2, sub = f & 3;
      int cw = sub * 16 + l15;
      float bias = qkvb[region * 512 + h * 64 + cw];
#pragma unroll
      for (int r = 0; r < 4; ++r) {
        int row = rt * 16 + q * 4 + r;
        if (row < 65) {
          float v = acc[rt][j][r] + bias;
          if      (region == 0) qf[row][cw] = v;
          else if (region == 1) kf[row][cw] = v;
          else                  vb[row][cw] = f2bf(v);
        }
      }
    }
  }
  __syncthreads();

  // ---- QK^T (289 4x4 tiles) ----
#pragma unroll
  for (int it = 0; it < 2; ++it) {
    int tile = it * 256 + tid;
    if (tile < 289) {
      int ti = (tile / 17) * 4, tj = (tile % 17) * 4;
      const float* qr[4]; const float* kr[4];
#pragma unroll
      for (int i = 0; i < 4; ++i) { qr[i] = qf[min(ti + i, 64)]; kr[i] = kf[min(tj + i, 64)]; }
      float a4[4][4] = {};
      for (int d = 0; d < 64; ++d) {
        float a[4], bvv[4];
#pragma unroll
        for (int i = 0; i < 4; ++i) { a[i] = qr[i][d]; bvv[i] = kr[i][d]; }
#pragma unroll
        for (int i = 0; i < 4; ++i)
#pragma unroll
          for (int j = 0; j < 4; ++j) a4[i][j] += a[i] * bvv[j];
      }
#pragma unroll
      for (int i = 0; i < 4; ++i)
        if (ti + i < 65)
#pragma unroll
          for (int j = 0; j < 4; ++j)
            if (tj + j < 65) ss[ti + i][tj + j] = a4[i][j] * 0.125f;
    }
  }
  __syncthreads();

  // ---- softmax rows ----
  if (tid < 65) {
    float mx = -1e30f;
    for (int j = 0; j < 65; ++j) mx = fmaxf(mx, ss[tid][j]);
    float s = 0.0f;
    for (int j = 0; j < 65; ++j) { float e = expf(ss[tid][j] - mx); ss[tid][j] = e; s += e; }
    float inv = 1.0f / s;
    for (int j = 0; j < 65; ++j) ss[tid][j] *= inv;
  }
  __syncthreads();

  // ---- PV (272 4x4 tiles), V from bf16 LDS ----
#pragma unroll
  for (int it = 0; it < 2; ++it) {
    int tile = it * 256 + tid;
    if (tile < 272) {
      int ti = (tile >> 4) * 4, d0 = (tile & 15) * 4;
      const float* sr[4];
#pragma unroll
      for (int i = 0; i < 4; ++i) sr[i] = ss[min(ti + i, 64)];
      float a4[4][4] = {};
      for (int j = 0; j < 65; ++j) {
        float v0 = bf2f(vb[j][d0]),   v1 = bf2f(vb[j][d0+1]);
        float v2 = bf2f(vb[j][d0+2]), v3 = bf2f(vb[j][d0+3]);
#pragma unroll
        for (int i = 0; i < 4; ++i) {
          float s = sr[i][j];
          a4[i][0] += s * v0; a4[i][1] += s * v1;
          a4[i][2] += s * v2; a4[i][3] += s * v3;
        }
      }
#pragma unroll
      for (int i = 0; i < 4; ++i)
        if (ti + i < 65) {
          ushort4 o;
          o.x = f2bf(a4[i][0]); o.y = f2bf(a4[i][1]);
          o.z = f2bf(a4[i][2]); o.w = f2bf(a4[i][3]);
          *(ushort4*)(obufb + pidx(b * NP1 + ti + i, h * 64 + d0, 8)) = o;
        }
    }
  }
}

// ---------------------------------------------------------------------------
// fused_row<KK,EPI>: 8 waves (512 thr), block owns 16 rows x 512 cols, K=KK.
// 65 blocks. Wave owns 64 cols (4 frags). Packed A (LDS-staged) and B
// (L2-streamed, 2-deep register prefetch).
// EPI 0: v+bias+residual(xs) -> LN(g,bb) -> xs (linear), xsb (packed)
// EPI 1: waves 0-3 u_pot -> outu ; waves 4-7 h + closed-form proj -> outh
// ---------------------------------------------------------------------------
template<int KK, int EPI>
__global__ __launch_bounds__(512) void fused_row(
    const u16* __restrict__ A, const u16* __restrict__ Bw,
    const float* __restrict__ bias,
    float* __restrict__ xs, u16* __restrict__ xsb,
    const float* __restrict__ g, const float* __restrict__ bb,
    const float* __restrict__ bias2,
    const float* __restrict__ marg, const float* __restrict__ xg,
    float* __restrict__ outu, float* __restrict__ outh)
{
  constexpr int KB  = KK >> 6;
  constexpr int KC  = (KK < 1024) ? KK : 1024;
  constexpr int NCH = KK / KC;
  __shared__ alignas(16) u16 Alds[16 * KC];      // <= 32 KB
  __shared__ float red[8][16];
  __shared__ float red2[8][16];
  const int tid = threadIdx.x, lane = tid & 63, wave = tid >> 6;
  const int l15 = lane & 15, q = lane >> 4;
  const int r0 = blockIdx.x * 16;
  const int rb = r0 >> 6, ro = r0 & 63;
  const int gc0 = wave * 64;                     // wave's 64 output cols
  const int nb = wave;                           // col block index

  f32x4 acc[4];
#pragma unroll
  for (int i = 0; i < 4; ++i) acc[i] = (f32x4){0,0,0,0};

  for (int ch = 0; ch < NCH; ++ch) {
    const int kc = ch * KC;
    __syncthreads();
    for (int idx = tid; idx < 2 * KC; idx += 512) {
      int rloc = idx & 15, cg = idx >> 4;
      int kbg = (kc >> 6) + (cg >> 3), cc = cg & 7;
      async16(A + ((size_t)(rb * KB + kbg) * 8 + cc) * 512 + (ro + rloc) * 8,
              &Alds[(size_t)idx * 8]);
    }
    asm volatile("s_waitcnt vmcnt(0)" ::: "memory");
    __syncthreads();

    constexpr int S = KC / 32;
    short8 bcur[4], bnxt[4];
    {
      int kk = kc + q * 8;
      int kbg = kk >> 6, cc = (kk & 63) >> 3;
#pragma unroll
      for (int i = 0; i < 4; ++i)
        bcur[i] = *(const short8*)&Bw[((size_t)(nb * KB + kbg) * 8 + cc) * 512
                                      + (i * 16 + l15) * 8];
    }
    for (int s = 0; s < S; ++s) {
      if (s + 1 < S) {
        int kk = kc + (s + 1) * 32 + q * 8;
        int kbg = kk >> 6, cc = (kk & 63) >> 3;
#pragma unroll
        for (int i = 0; i < 4; ++i)
          bnxt[i] = *(const short8*)&Bw[((size_t)(nb * KB + kbg) * 8 + cc) * 512
                                        + (i * 16 + l15) * 8];
      }
      short8 af = *(const short8*)&Alds[(size_t)((s * 4 + q) * 16 + l15) * 8];
#pragma unroll
      for (int i = 0; i < 4; ++i)
        acc[i] = __builtin_amdgcn_mfma_f32_16x16x32_bf16(af, bcur[i], acc[i], 0, 0, 0);
#pragma unroll
      for (int i = 0; i < 4; ++i) bcur[i] = bnxt[i];
    }
  }

  // lane's elements: row = q*4+r (local), col = gc0 + i*16 + l15
  if (EPI == 0) {
    float vv[4][4];
#pragma unroll
    for (int i = 0; i < 4; ++i) {
      int col = gc0 + i*16 + l15;
      float bcol = bias[col];
#pragma unroll
      for (int r = 0; r < 4; ++r) {
        int gr = r0 + q*4 + r;
        vv[i][r] = acc[i][r] + bcol + xs[(size_t)gr * Dm + col];
      }
    }
    float ps[4];
#pragma unroll
    for (int r = 0; r < 4; ++r) {
      float s = 0.f;
#pragma unroll
      for (int i = 0; i < 4; ++i) s += vv[i][r];
      ps[r] = s;
    }
#pragma unroll
    for (int o = 1; o < 16; o <<= 1)
#pragma unroll
      for (int r = 0; r < 4; ++r) ps[r] += __shfl_xor(ps[r], o, 64);
    if (l15 == 0)
#pragma unroll
      for (int r = 0; r < 4; ++r) red[wave][q*4 + r] = ps[r];
    __syncthreads();
    float mu[4];
#pragma unroll
    for (int r = 0; r < 4; ++r) {
      int rr = q*4 + r;
      float s = 0.f;
#pragma unroll
      for (int w = 0; w < 8; ++w) s += red[w][rr];
      mu[r] = s * (1.0f/512.0f);
    }
    float ps2[4];
#pragma unroll
    for (int r = 0; r < 4; ++r) {
      float s = 0.f;
#pragma unroll
      for (int i = 0; i < 4; ++i) { float d = vv[i][r] - mu[r]; s += d * d; }
      ps2[r] = s;
    }
#pragma unroll
    for (int o = 1; o < 16; o <<= 1)
#pragma unroll
      for (int r = 0; r < 4; ++r) ps2[r] += __shfl_xor(ps2[r], o, 64);
    if (l15 == 0)
#pragma unroll
      for (int r = 0; r < 4; ++r) red2[wave][q*4 + r] = ps2[r];
    __syncthreads();
    float inv[4];
#pragma unroll
    for (int r = 0; r < 4; ++r) {
      int rr = q*4 + r;
      float s = 0.f;
#pragma unroll
      for (int w = 0; w < 8; ++w) s += red2[w][rr];
      inv[r] = rsqrtf(s * (1.0f/512.0f) + 1e-5f);
    }
#pragma unroll
    for (int i = 0; i < 4; ++i) {
      int col = gc0 + i*16 + l15;
      float gc = g[col], bc = bb[col];
#pragma unroll
      for (int r = 0; r < 4; ++r) {
        int gr = r0 + q*4 + r;
        float y = (vv[i][r] - mu[r]) * inv[r] * gc + bc;
        xs[(size_t)gr * Dm + col] = y;
        xsb[pidx(gr, col, 8)] = f2bf(y);
      }
    }
  } else {
    // EPI 1: waves 4-7 own h cols; reduce, one uniform barrier, both write.
    float va[4][4];
    if (wave >= 4) {
      float wd[4] = {0.f,0.f,0.f,0.f}, ms[4] = {0.f,0.f,0.f,0.f};
#pragma unroll
      for (int i = 0; i < 4; ++i) {
        int hcol = (gc0 - 256) + i*16 + l15;
        float bcol = bias2[hcol];
        float xv = xg[hcol];
#pragma unroll
        for (int r = 0; r < 4; ++r) {
          int gr = r0 + q*4 + r;
          float a = acc[i][r] + bcol;
          va[i][r] = a;
          float uvm = marg[(size_t)gr * MG + hcol];
          wd[r] += uvm * (f_closed(a) - xv);
          ms[r] += uvm;
        }
      }
#pragma unroll
      for (int o = 1; o < 16; o <<= 1)
#pragma unroll
        for (int r = 0; r < 4; ++r) {
          wd[r] += __shfl_xor(wd[r], o, 64);
          ms[r] += __shfl_xor(ms[r], o, 64);
        }
      if (l15 == 0)
#pragma unroll
        for (int r = 0; r < 4; ++r) {
          red[wave][q*4 + r]  = wd[r];
          red2[wave][q*4 + r] = ms[r];
        }
    }
    __syncthreads();
    if (wave < 4) {
#pragma unroll
      for (int i = 0; i < 4; ++i) {
        int col = gc0 + i*16 + l15;
        float bcol = bias[col];
#pragma unroll
        for (int r = 0; r < 4; ++r) {
          int gr = r0 + q*4 + r;
          outu[(size_t)gr * MG + col] = acc[i][r] + bcol;
        }
      }
    } else {
#pragma unroll
      for (int i = 0; i < 4; ++i) {
        int hcol = (gc0 - 256) + i*16 + l15;
#pragma unroll
        for (int r = 0; r < 4; ++r) {
          int rr = q*4 + r;
          int gr = r0 + rr;
          int bI = gr / NP1, n = gr - bI * NP1;
          if (n < 64) {
            float num = red[4][rr] + red[5][rr] + red[6][rr] + red[7][rr];
            float den = red2[4][rr] + red2[5][rr] + red2[6][rr] + red2[7][rr];
            float corr = num / (den + 1e-8f);
            outh[(size_t)(bI * 64 + n) * MG + hcol] = va[i][r] - corr;
          }
        }
      }
    }
  }
}

// ---------------------------------------------------------------------------
extern "C" void kernel_launch(void* const* d_in, const int* in_sizes, int n_in,
                              void* d_out, int out_size, void* d_ws, size_t ws_size,
                              hipStream_t stream)
{
  const float* marg   = (const float*)d_in[0];
  const float* xg     = (const float*)d_in[1];
  const float* conv_w = (const float*)d_in[2];
  const float* conv_b = (const float*)d_in[3];
  const float* fc_w   = (const float*)d_in[4];
  const float* fc_b   = (const float*)d_in[5];
  const float* ln0_g  = (const float*)d_in[6];
  const float* ln0_b  = (const float*)d_in[7];
  const float* pos    = (const float*)d_in[8];
  const float* qkv_w  = (const float*)d_in[9];
  const float* qkv_b  = (const float*)d_in[10];
  const float* out_w  = (const float*)d_in[11];
  const float* out_b  = (const float*)d_in[12];
  const float* ln1_g  = (const float*)d_in[13];
  const float* ln1_b  = (const float*)d_in[14];
  const float* ff1_w  = (const float*)d_in[15];
  const float* ff1_b  = (const float*)d_in[16];
  const float* ff2_w  = (const float*)d_in[17];
  const float* ff2_b  = (const float*)d_in[18];
  const float* ln2_g  = (const float*)d_in[19];
  const float* ln2_b  = (const float*)d_in[20];
  const float* u_w    = (const float*)d_in[21];
  const float* u_b    = (const float*)d_in[22];
  const float* h_w    = (const float*)d_in[23];
  const float* h_b    = (const float*)d_in[24];
  float* out = (float*)d_out;

  float* ws = (float*)d_ws;
  float* xs      = ws;                              // 532480 f32 (linear)
  u16*   xsb     = (u16*)(ws + 2129920);            // 1088x512 packed
  u16*   obufb   = (u16*)(ws + 2408448);            // 1088x512 packed
  u16*   ffb     = (u16*)(ws + 2686976);            // 1088x2048 packed
  u16*   wbf     = (u16*)(ws + 3801088);            // 9699328 u16 packed

  const u16* qkv_bw = wbf;
  const u16* out_bw = wbf + 2359296;
  const u16* ff1_bw = wbf + 3145728;
  const u16* ff2_bw = wbf + 6291456;
  const u16* uh_bw  = wbf + 9437184;   // u rows 0..255, h rows 256..511

  prep_kernel<<<772, 256, 0, stream>>>(
      qkv_w, out_w, ff1_w, ff2_w, u_w, h_w, wbf,
      marg, conv_w, conv_b, fc_w, fc_b, ln0_g, ln0_b, pos, xs, xsb);

  for (int l = 0; l < 3; ++l) {
    fused_qkv_attn<<<128, 256, 0, stream>>>(
        xsb, qkv_bw + (size_t)l*786432, qkv_b + l*1536, obufb);
    fused_row<512, 0><<<65, 512, 0, stream>>>(
        obufb, out_bw + (size_t)l*262144, out_b + l*512,
        xs, xsb, ln1_g + l*512, ln1_b + l*512,
        nullptr, nullptr, nullptr, nullptr, nullptr);
    gemm_mfma<1><<<dim3(32, 17), 256, 0, stream>>>(
        xsb, ff1_bw + (size_t)l*1048576, ff1_b + l*2048, nullptr,
        ffb, BT, 2048, 512);
    fused_row<2048, 0><<<65, 512, 0, stream>>>(
        ffb, ff2_bw + (size_t)l*1048576, ff2_b + l*512,
        xs, xsb, ln2_g + l*512, ln2_b + l*512,
        nullptr, nullptr, nullptr, nullptr, nullptr);
  }

  fused_row<512, 1><<<65, 512, 0, stream>>>(
      xsb, uh_bw, u_b,
      nullptr, nullptr, nullptr, nullptr,
      h_b, marg, xg, out, out + 1040*256);
}